// Round 12
// baseline (441.203 us; speedup 1.0000x reference)
//
#include <hip/hip_runtime.h>
#include <hip/hip_bf16.h>
#include <stdint.h>

// MoELayer: B=4, T=2048, D=1024, E=8, H=2048, K=2
#define ND    1024
#define NE    8
#define NH    2048
#define NTOK  8192
#define NPAIR (NTOK*2)

typedef unsigned short u16;
typedef __attribute__((ext_vector_type(8))) short bf16x8;
typedef __attribute__((ext_vector_type(4))) float f32x4;

__device__ __forceinline__ u16 f2bf(float f) {
    union { float f; unsigned u; } v; v.f = f;
    return (u16)((v.u + 0x7fffu + ((v.u >> 16) & 1u)) >> 16);   // RNE
}

__device__ __forceinline__ void gl_lds16(const void* g, void* l) {
    __builtin_amdgcn_global_load_lds(
        (const __attribute__((address_space(1))) unsigned int*)g,
        (__attribute__((address_space(3))) unsigned int*)l, 16, 0, 0);
}

// ctrl layout (ints):
#define CTRL_OFFS  16
#define CTRL_BC    32
#define CTRL_BB    288
#define CTRL_TOPK  544

// ---------------- kernel 1: router (wave per token, NO atomics) ----------------
__global__ __launch_bounds__(256) void router_topk2(
    const float* __restrict__ x, const float* __restrict__ rw,
    int* __restrict__ topk_idx, float* __restrict__ topk_w)
{
    const int n    = blockIdx.x * 4 + (threadIdx.x >> 6);
    const int lane = threadIdx.x & 63;
    const float* xr = x + (size_t)n * ND;
    float4 xv[4];
    #pragma unroll
    for (int i = 0; i < 4; ++i) xv[i] = *(const float4*)(xr + lane*16 + i*4);

    float lg[NE];
    #pragma unroll
    for (int e = 0; e < NE; ++e) {
        const float* wr_ = rw + (size_t)e * ND + lane*16;
        float a = 0.f;
        #pragma unroll
        for (int i = 0; i < 4; ++i) {
            float4 wv = *(const float4*)(wr_ + i*4);
            a += xv[i].x*wv.x + xv[i].y*wv.y + xv[i].z*wv.z + xv[i].w*wv.w;
        }
        #pragma unroll
        for (int s = 32; s; s >>= 1) a += __shfl_xor(a, s);
        lg[e] = a;
    }
    if (lane == 0) {
        int i0 = 0; float v0 = lg[0];
        #pragma unroll
        for (int i = 1; i < NE; ++i) { float v = lg[i]; if (v > v0) { v0 = v; i0 = i; } }
        int i1 = -1; float v1 = -3.4e38f;
        #pragma unroll
        for (int i = 0; i < NE; ++i) {
            if (i == i0) continue;
            float v = lg[i]; if (v > v1) { v1 = v; i1 = i; }
        }
        float w0 = 1.f / (1.f + expf(v1 - v0));
        topk_idx[n*2]   = i0;  topk_idx[n*2+1] = i1;
        topk_w [n*2]    = w0;  topk_w [n*2+1]  = 1.f - w0;
    }
}

// ---------------- kernel 2: per-block expert histogram ----------------
__global__ __launch_bounds__(256) void hist_blocks(
    const int* __restrict__ topk_idx, int* __restrict__ blockcounts)
{
    __shared__ int c[NE];
    const int tid = threadIdx.x;
    if (tid < NE) c[tid] = 0;
    __syncthreads();
    const int n = blockIdx.x * 256 + tid;
    atomicAdd(&c[topk_idx[n*2]],   1);
    atomicAdd(&c[topk_idx[n*2+1]], 1);
    __syncthreads();
    if (tid < NE) blockcounts[blockIdx.x * NE + tid] = c[tid];
}

// ---------------- kernel 3: prefix (1 wave) ----------------
__global__ void prefix2(int* __restrict__ ctrl)
{
    const int e = threadIdx.x;
    const int* bc = ctrl + CTRL_BC;
    int* offsets  = ctrl + CTRL_OFFS;
    int* bbase    = ctrl + CTRL_BB;
    if (e < NE) {
        int run = 0;
        int tmp[32];
        #pragma unroll
        for (int b = 0; b < 32; ++b) { tmp[b] = run; run += bc[b*NE + e]; }
        int total = run, pre = 0;
        #pragma unroll
        for (int i = 0; i < NE; ++i) {
            int v = __shfl(total, i);
            if (i < e) pre += v;
        }
        offsets[e] = pre;
        if (e == NE-1) offsets[NE] = pre + total;
        #pragma unroll
        for (int b = 0; b < 32; ++b) bbase[b*NE + e] = pre + tmp[b];
    }
}

// ---------------- kernel 4: stable deterministic scatter ----------------
__global__ __launch_bounds__(256) void scatter2(
    const int* __restrict__ topk_idx, const float* __restrict__ topk_w,
    const int* __restrict__ ctrl,
    int* __restrict__ bucket_tok, float* __restrict__ bucket_gw)
{
    __shared__ int wc[4][NE];
    const int b = blockIdx.x, tid = threadIdx.x;
    const int w = tid >> 6, l = tid & 63;
    const int n = b*256 + tid;
    const int e0 = topk_idx[n*2], e1 = topk_idx[n*2+1];
    const unsigned long long lt = (1ULL << l) - 1ULL;

    int rank0 = 0, rank1 = 0;
    #pragma unroll
    for (int e = 0; e < NE; ++e) {
        unsigned long long m0 = __ballot(e0 == e);
        unsigned long long m1 = __ballot(e1 == e);
        int c0 = __popcll(m0);
        if (e0 == e) rank0 = __popcll(m0 & lt);
        if (e1 == e) rank1 = c0 + __popcll(m1 & lt);
        if (l == 0) wc[w][e] = c0 + __popcll(m1);
    }
    __syncthreads();
    const int* bbase = ctrl + CTRL_BB;
    int wo0 = 0, wo1 = 0;
    #pragma unroll
    for (int w2 = 0; w2 < 4; ++w2) {
        if (w2 < w) { wo0 += wc[w2][e0]; wo1 += wc[w2][e1]; }
    }
    int p0 = bbase[b*NE + e0] + wo0 + rank0;
    int p1 = bbase[b*NE + e1] + wo1 + rank1;
    bucket_tok[p0] = n;  bucket_gw[p0] = topk_w[n*2];
    bucket_tok[p1] = n;  bucket_gw[p1] = topk_w[n*2+1];
}

// ---------------- kernel T: transpose + fp32->bf16 ----------------
__global__ __launch_bounds__(256) void transpose_cvt(
    const float* __restrict__ src, u16* __restrict__ dst, int R, int C)
{
    __shared__ float tb[64][65];
    const int tpc = C >> 6;
    const int tr = blockIdx.x / tpc;
    const int tc = blockIdx.x % tpc;
    src += (size_t)blockIdx.y * R * C;
    dst += (size_t)blockIdx.y * R * C;
    const int tid = threadIdx.x;
    #pragma unroll
    for (int i = 0; i < 4; ++i) {
        int idx = i*256 + tid;
        int r = idx >> 4, c4 = (idx & 15) * 4;
        float4 v = *(const float4*)(src + (size_t)(tr*64 + r)*C + tc*64 + c4);
        tb[r][c4] = v.x; tb[r][c4+1] = v.y; tb[r][c4+2] = v.z; tb[r][c4+3] = v.w;
    }
    __syncthreads();
    #pragma unroll
    for (int i = 0; i < 2; ++i) {
        int idx = i*256 + tid;
        int c = idx >> 3, s8 = (idx & 7) * 8;
        union { u16 u[8]; uint4 v; } pk;
        #pragma unroll
        for (int j = 0; j < 8; ++j) pk.u[j] = f2bf(tb[s8 + j][c]);
        *(uint4*)(dst + (size_t)(tc*64 + c)*R + tr*64 + s8) = pk.v;
    }
}

// ---------------- kernel X: fp32 -> bf16 convert of x (no gather) ----------------
__global__ __launch_bounds__(256) void cvt_x(
    const float* __restrict__ x, u16* __restrict__ xbf)
{
    const int i = (blockIdx.x * 256 + threadIdx.x) * 8;
    float4 a = *(const float4*)(x + i);
    float4 b = *(const float4*)(x + i + 4);
    union { u16 u[8]; uint4 v; } p;
    p.u[0]=f2bf(a.x); p.u[1]=f2bf(a.y); p.u[2]=f2bf(a.z); p.u[3]=f2bf(a.w);
    p.u[4]=f2bf(b.x); p.u[5]=f2bf(b.y); p.u[6]=f2bf(b.z); p.u[7]=f2bf(b.w);
    *(uint4*)(xbf + i) = p.v;
}

// ---------------- pass GEMM: 128x128, BK=64, reg-staged A + LDS dbuf B ----------------
// r7 structure (proven 118us) with A's LDS round-trip removed: A fragments are
// loaded straight into registers (afA/afB double-buffer, static indexing),
// issued right after the barrier so they land under the compute phase (same
// lead as r7's staging). Per-lane A addresses allow free bucket_tok gather in
// pass 1 (GATHER=1, A source = xbf). B: gl_lds dbuf + XOR swizzle, unchanged.
// LDS 32KB (B only); 4 waves 2Mx2N, wave owns 64x64.
// XCD swizzle: w=(bid&7)<<S|bid>>3 -> each XCD owns one expert (L2 locality).
// EPI=0: A1 = bf16(relu^2(C)).  EPI=1: out[tok] += gate * C (f32 atomics).
template<int KSTEPS, int EPI, int NT_TILES, int WPE_SHIFT, int GATHER>
__global__ __launch_bounds__(256, 2) void pass_gemm(
    const u16* __restrict__ Amat, const u16* __restrict__ Bmat,
    const int* __restrict__ bucket_tok, const float* __restrict__ bucket_gw,
    const int* __restrict__ ctrl,
    u16* __restrict__ A1out, float* __restrict__ out)
{
    const int K   = KSTEPS * 64;
    const int bid = blockIdx.x;
    const int w   = ((bid & 7) << WPE_SHIFT) | (bid >> 3);   // bijective chunked swizzle
    const int e   = w >> WPE_SHIFT;
    const int r   = w & ((1 << WPE_SHIFT) - 1);
    const int nt0 = (r % NT_TILES) * 128;                    // n fastest: A-panel L2 reuse
    const int mt0 = (r / NT_TILES) * 128;
    const int* offsets = ctrl + CTRL_OFFS;
    const int beg = offsets[e];
    const int cnt = offsets[e+1] - beg;
    if (mt0 >= cnt) return;

    extern __shared__ u16 sm[];   // B only: [2][128][64] bf16 = 32KB

    const int tid  = threadIdx.x;
    const int wv   = tid >> 6;
    const int lane = tid & 63;
    const int l15  = lane & 15;
    const int grp  = lane >> 4;
    const int wr   = wv >> 1, wc = wv & 1;

    const u16* Bb = Bmat + (size_t)e * NH * ND;

    const int rsub  = lane >> 3;     // row within 8-row group
    const int csrc0 = lane & 7;      // source chunk pre-swizzle

    // per-lane A fragment base pointers (4 m-frags; gather folded in for pass 1)
    const u16* abase[4];
    #pragma unroll
    for (int mt = 0; mt < 4; ++mt) {
        int ml = mt0 + wr*64 + mt*16 + l15;
        if (ml > cnt - 1) ml = cnt - 1;            // clamp (dup loads, masked at epilogue)
        if (GATHER) abase[mt] = Amat + (size_t)bucket_tok[beg + ml] * ND + grp*8;
        else        abase[mt] = Amat + (size_t)(beg + ml) * K + grp*8;
    }

    // stage one B K-tile: 128 rows x 64 k (4 gl_lds16 per wave)
    auto stageB = [&](int buf, int kt) {
        #pragma unroll
        for (int c = 0; c < 4; ++c) {
            int row = c*32 + wv*8 + rsub;
            int chunk = csrc0 ^ (row & 7);            // inverse-swizzled source
            const u16* gb = Bb + (size_t)(nt0 + row) * K + kt*64 + chunk*8;
            gl_lds16(gb, sm + buf*8192 + c*2048 + wv*512);
        }
    };

    auto load_af = [&](bf16x8 (&af)[2][4], int kt) {
        #pragma unroll
        for (int kk = 0; kk < 2; ++kk)
            #pragma unroll
            for (int mt = 0; mt < 4; ++mt)
                af[kk][mt] = *(const bf16x8*)(abase[mt] + kt*64 + kk*32);
    };

    f32x4 acc[4][4];
    #pragma unroll
    for (int mt = 0; mt < 4; ++mt)
        #pragma unroll
        for (int nt = 0; nt < 4; ++nt) acc[mt][nt] = 0;

    auto compute = [&](bf16x8 (&af)[2][4], int cur) {
        const char* Bs = (const char*)sm + cur*16384;
        #pragma unroll
        for (int kk = 0; kk < 2; ++kk) {
            bf16x8 bfr[4];
            #pragma unroll
            for (int nt = 0; nt < 4; ++nt) {
                int row = wc*64 + nt*16 + l15;
                int kb  = ((kk*32 + grp*8)*2) ^ ((row & 7) << 4);   // swizzled read
                bfr[nt] = *(const bf16x8*)(Bs + row*128 + kb);
            }
            #pragma unroll
            for (int mt = 0; mt < 4; ++mt)
                #pragma unroll
                for (int nt = 0; nt < 4; ++nt)
                    acc[mt][nt] = __builtin_amdgcn_mfma_f32_16x16x32_bf16(
                        af[kk][mt], bfr[nt], acc[mt][nt], 0,0,0);
        }
    };

    bf16x8 afA[2][4], afB[2][4];
    load_af(afA, 0);
    stageB(0, 0);
    for (int kt = 0; kt < KSTEPS; kt += 2) {
        __syncthreads();                               // buf0/afA(kt) landed; prev reads done
        if (kt + 1 < KSTEPS) { load_af(afB, kt + 1); stageB(1, kt + 1); }
        compute(afA, 0);
        __syncthreads();                               // buf1/afB landed; buf0 reads done
        if (kt + 2 < KSTEPS) { load_af(afA, kt + 2); stageB(0, kt + 2); }
        compute(afB, 1);
    }

    // epilogue: D row(token) = grp*4+r, col = l15 (verified mapping)
    #pragma unroll
    for (int mt = 0; mt < 4; ++mt) {
        #pragma unroll
        for (int r4 = 0; r4 < 4; ++r4) {
            int ml = mt0 + wr*64 + mt*16 + grp*4 + r4;
            if (ml >= cnt) continue;
            if (EPI == 0) {
                u16* dst = A1out + (size_t)(beg + ml) * NH + nt0 + wc*64 + l15;
                #pragma unroll
                for (int nt = 0; nt < 4; ++nt) {
                    float v = fmaxf(acc[mt][nt][r4], 0.f);
                    dst[nt*16] = f2bf(v * v);
                }
            } else {
                int   p = bucket_tok[beg + ml];
                float g = bucket_gw [beg + ml];
                float* orow = out + (size_t)p * ND + nt0 + wc*64 + l15;
                #pragma unroll
                for (int nt = 0; nt < 4; ++nt)
                    atomicAdd(orow + nt*16, g * acc[mt][nt][r4]);
            }
        }
    }
}

// ---------------- launch ----------------
extern "C" void kernel_launch(void* const* d_in, const int* in_sizes, int n_in,
                              void* d_out, int out_size, void* d_ws, size_t ws_size,
                              hipStream_t stream) {
    const float* x  = (const float*)d_in[0];
    const float* rw = (const float*)d_in[1];
    const float* w1 = (const float*)d_in[2];
    const float* w2 = (const float*)d_in[3];
    float* out = (float*)d_out;

    int*   ctrl        = (int*)d_ws;
    int*   blockcounts = ctrl + CTRL_BC;
    int*   topk_idx    = ctrl + CTRL_TOPK;
    float* topk_w      = (float*)(topk_idx + NPAIR);
    int*   bucket_tok  = (int*)(topk_w + NPAIR);
    float* bucket_gw   = (float*)(bucket_tok + NPAIR);

    const size_t CTRL_BYTES = (size_t)1 << 19;                       // 512 KB
    const size_t WT_BYTES   = (size_t)NE * NH * ND * sizeof(u16);    // 32 MB

    hipMemsetAsync(d_out, 0, (size_t)NTOK * ND * sizeof(float), stream);

    router_topk2<<<NTOK/4, 256, 0, stream>>>(x, rw, topk_idx, topk_w);
    hist_blocks<<<NTOK/256, 256, 0, stream>>>(topk_idx, blockcounts);
    prefix2<<<1, 64, 0, stream>>>(ctrl);
    scatter2<<<NTOK/256, 256, 0, stream>>>(topk_idx, topk_w, ctrl, bucket_tok, bucket_gw);

    u16* w1t = (u16*)((char*)d_ws + CTRL_BYTES);
    u16* shr = (u16*)((char*)d_ws + CTRL_BYTES + WT_BYTES);      // xbf (16MB) then w2t (32MB)
    u16* A1  = (u16*)((char*)d_ws + CTRL_BYTES + 2*WT_BYTES);

    transpose_cvt<<<dim3(512, NE), 256, 0, stream>>>(w1, w1t, ND, NH);
    cvt_x<<<NTOK*ND/2048, 256, 0, stream>>>(x, shr);             // xbf

    const size_t shbytes = 16384 * sizeof(u16);   // 32 KB (B dbuf only)

    // pass 1: A = xbf gathered via bucket_tok; per-expert grid = 128 m x 16 n = 1<<11
    pass_gemm<16, 0, 16, 11, 1><<<8 << 11, 256, shbytes, stream>>>(
        shr, w1t, bucket_tok, bucket_gw, ctrl, A1, nullptr);

    transpose_cvt<<<dim3(512, NE), 256, 0, stream>>>(w2, shr, NH, ND);   // w2t (overwrites xbf)

    // pass 2: A = A1 direct; per-expert grid = 128 m x 8 n = 1<<10
    pass_gemm<32, 1, 8, 10, 0><<<8 << 10, 256, shbytes, stream>>>(
        A1, shr, bucket_tok, bucket_gw, ctrl, nullptr, out);
}

// Round 13
// 330.666 us; speedup vs baseline: 1.3343x; 1.3343x over previous
//
#include <hip/hip_runtime.h>
#include <hip/hip_bf16.h>
#include <stdint.h>

// MoELayer: B=4, T=2048, D=1024, E=8, H=2048, K=2
#define ND    1024
#define NE    8
#define NH    2048
#define NTOK  8192
#define NPAIR (NTOK*2)

typedef unsigned short u16;
typedef __attribute__((ext_vector_type(8))) short bf16x8;
typedef __attribute__((ext_vector_type(4))) float f32x4;

__device__ __forceinline__ u16 f2bf(float f) {
    union { float f; unsigned u; } v; v.f = f;
    return (u16)((v.u + 0x7fffu + ((v.u >> 16) & 1u)) >> 16);   // RNE
}

__device__ __forceinline__ void gl_lds16(const void* g, void* l) {
    __builtin_amdgcn_global_load_lds(
        (const __attribute__((address_space(1))) unsigned int*)g,
        (__attribute__((address_space(3))) unsigned int*)l, 16, 0, 0);
}

// LDS byte offset of an LDS pointer (AS(3) pointers are 32-bit offsets)
__device__ __forceinline__ unsigned ldsoff(const void* p) {
    return (unsigned)(size_t)(const __attribute__((address_space(3))) char*)p;
}

// ctrl layout (ints):
#define CTRL_OFFS  16
#define CTRL_BC    32
#define CTRL_BB    288
#define CTRL_TOPK  544

// ---------------- kernel 1: router (wave per token, NO atomics) ----------------
__global__ __launch_bounds__(256) void router_topk2(
    const float* __restrict__ x, const float* __restrict__ rw,
    int* __restrict__ topk_idx, float* __restrict__ topk_w)
{
    const int n    = blockIdx.x * 4 + (threadIdx.x >> 6);
    const int lane = threadIdx.x & 63;
    const float* xr = x + (size_t)n * ND;
    float4 xv[4];
    #pragma unroll
    for (int i = 0; i < 4; ++i) xv[i] = *(const float4*)(xr + lane*16 + i*4);

    float lg[NE];
    #pragma unroll
    for (int e = 0; e < NE; ++e) {
        const float* wr_ = rw + (size_t)e * ND + lane*16;
        float a = 0.f;
        #pragma unroll
        for (int i = 0; i < 4; ++i) {
            float4 wv = *(const float4*)(wr_ + i*4);
            a += xv[i].x*wv.x + xv[i].y*wv.y + xv[i].z*wv.z + xv[i].w*wv.w;
        }
        #pragma unroll
        for (int s = 32; s; s >>= 1) a += __shfl_xor(a, s);
        lg[e] = a;
    }
    if (lane == 0) {
        int i0 = 0; float v0 = lg[0];
        #pragma unroll
        for (int i = 1; i < NE; ++i) { float v = lg[i]; if (v > v0) { v0 = v; i0 = i; } }
        int i1 = -1; float v1 = -3.4e38f;
        #pragma unroll
        for (int i = 0; i < NE; ++i) {
            if (i == i0) continue;
            float v = lg[i]; if (v > v1) { v1 = v; i1 = i; }
        }
        float w0 = 1.f / (1.f + expf(v1 - v0));
        topk_idx[n*2]   = i0;  topk_idx[n*2+1] = i1;
        topk_w [n*2]    = w0;  topk_w [n*2+1]  = 1.f - w0;
    }
}

// ---------------- kernel 2: per-block expert histogram ----------------
__global__ __launch_bounds__(256) void hist_blocks(
    const int* __restrict__ topk_idx, int* __restrict__ blockcounts)
{
    __shared__ int c[NE];
    const int tid = threadIdx.x;
    if (tid < NE) c[tid] = 0;
    __syncthreads();
    const int n = blockIdx.x * 256 + tid;
    atomicAdd(&c[topk_idx[n*2]],   1);
    atomicAdd(&c[topk_idx[n*2+1]], 1);
    __syncthreads();
    if (tid < NE) blockcounts[blockIdx.x * NE + tid] = c[tid];
}

// ---------------- kernel 3: prefix (1 wave) ----------------
__global__ void prefix2(int* __restrict__ ctrl)
{
    const int e = threadIdx.x;
    const int* bc = ctrl + CTRL_BC;
    int* offsets  = ctrl + CTRL_OFFS;
    int* bbase    = ctrl + CTRL_BB;
    if (e < NE) {
        int run = 0;
        int tmp[32];
        #pragma unroll
        for (int b = 0; b < 32; ++b) { tmp[b] = run; run += bc[b*NE + e]; }
        int total = run, pre = 0;
        #pragma unroll
        for (int i = 0; i < NE; ++i) {
            int v = __shfl(total, i);
            if (i < e) pre += v;
        }
        offsets[e] = pre;
        if (e == NE-1) offsets[NE] = pre + total;
        #pragma unroll
        for (int b = 0; b < 32; ++b) bbase[b*NE + e] = pre + tmp[b];
    }
}

// ---------------- kernel 4: stable deterministic scatter ----------------
__global__ __launch_bounds__(256) void scatter2(
    const int* __restrict__ topk_idx, const float* __restrict__ topk_w,
    const int* __restrict__ ctrl,
    int* __restrict__ bucket_tok, float* __restrict__ bucket_gw)
{
    __shared__ int wc[4][NE];
    const int b = blockIdx.x, tid = threadIdx.x;
    const int w = tid >> 6, l = tid & 63;
    const int n = b*256 + tid;
    const int e0 = topk_idx[n*2], e1 = topk_idx[n*2+1];
    const unsigned long long lt = (1ULL << l) - 1ULL;

    int rank0 = 0, rank1 = 0;
    #pragma unroll
    for (int e = 0; e < NE; ++e) {
        unsigned long long m0 = __ballot(e0 == e);
        unsigned long long m1 = __ballot(e1 == e);
        int c0 = __popcll(m0);
        if (e0 == e) rank0 = __popcll(m0 & lt);
        if (e1 == e) rank1 = c0 + __popcll(m1 & lt);
        if (l == 0) wc[w][e] = c0 + __popcll(m1);
    }
    __syncthreads();
    const int* bbase = ctrl + CTRL_BB;
    int wo0 = 0, wo1 = 0;
    #pragma unroll
    for (int w2 = 0; w2 < 4; ++w2) {
        if (w2 < w) { wo0 += wc[w2][e0]; wo1 += wc[w2][e1]; }
    }
    int p0 = bbase[b*NE + e0] + wo0 + rank0;
    int p1 = bbase[b*NE + e1] + wo1 + rank1;
    bucket_tok[p0] = n;  bucket_gw[p0] = topk_w[n*2];
    bucket_tok[p1] = n;  bucket_gw[p1] = topk_w[n*2+1];
}

// ---------------- kernel T: transpose + fp32->bf16 ----------------
__global__ __launch_bounds__(256) void transpose_cvt(
    const float* __restrict__ src, u16* __restrict__ dst, int R, int C)
{
    __shared__ float tb[64][65];
    const int tpc = C >> 6;
    const int tr = blockIdx.x / tpc;
    const int tc = blockIdx.x % tpc;
    src += (size_t)blockIdx.y * R * C;
    dst += (size_t)blockIdx.y * R * C;
    const int tid = threadIdx.x;
    #pragma unroll
    for (int i = 0; i < 4; ++i) {
        int idx = i*256 + tid;
        int r = idx >> 4, c4 = (idx & 15) * 4;
        float4 v = *(const float4*)(src + (size_t)(tr*64 + r)*C + tc*64 + c4);
        tb[r][c4] = v.x; tb[r][c4+1] = v.y; tb[r][c4+2] = v.z; tb[r][c4+3] = v.w;
    }
    __syncthreads();
    #pragma unroll
    for (int i = 0; i < 2; ++i) {
        int idx = i*256 + tid;
        int c = idx >> 3, s8 = (idx & 7) * 8;
        union { u16 u[8]; uint4 v; } pk;
        #pragma unroll
        for (int j = 0; j < 8; ++j) pk.u[j] = f2bf(tb[s8 + j][c]);
        *(uint4*)(dst + (size_t)(tc*64 + c)*R + tr*64 + s8) = pk.v;
    }
}

// ---------------- kernel G: gather + fp32->bf16 ----------------
__global__ __launch_bounds__(256) void gather_cvt(
    const float* __restrict__ x, const int* __restrict__ bucket_tok, u16* __restrict__ Xg)
{
    const int pair = blockIdx.x * 4 + (threadIdx.x >> 6);
    const int lane = threadIdx.x & 63;
    const float* xr = x + (size_t)bucket_tok[pair] * ND;
    u16* dr = Xg + (size_t)pair * ND;
    const int d0 = lane * 16;
    float4 a = *(const float4*)(xr + d0);
    float4 b = *(const float4*)(xr + d0 + 4);
    float4 c = *(const float4*)(xr + d0 + 8);
    float4 d = *(const float4*)(xr + d0 + 12);
    union { u16 u[8]; uint4 v; } p0, p1;
    p0.u[0]=f2bf(a.x); p0.u[1]=f2bf(a.y); p0.u[2]=f2bf(a.z); p0.u[3]=f2bf(a.w);
    p0.u[4]=f2bf(b.x); p0.u[5]=f2bf(b.y); p0.u[6]=f2bf(b.z); p0.u[7]=f2bf(b.w);
    p1.u[0]=f2bf(c.x); p1.u[1]=f2bf(c.y); p1.u[2]=f2bf(c.z); p1.u[3]=f2bf(c.w);
    p1.u[4]=f2bf(d.x); p1.u[5]=f2bf(d.y); p1.u[6]=f2bf(d.z); p1.u[7]=f2bf(d.w);
    *(uint4*)(dr + d0)     = p0.v;
    *(uint4*)(dr + d0 + 8) = p1.v;
}

// ---------------- pass GEMM: 256m x 128n, BK=64, 8 waves, 3-buf counted-vmcnt ----------
// r9's proven-correct bookkeeping with COMPILER-INVISIBLE fragment reads:
// all 16 ds_read_b128 are inline asm (LDS byte offsets), so hipcc cannot
// insert its conservative vmcnt(0) drain between gl_lds staging and the
// reads (the r8/r9 stall). Ordering is carried entirely by explicit waits:
//   top of step kt: s_waitcnt vmcnt(6)  -> retires S(kt)   (S = 6 loads)
//                   s_barrier            -> true for all waves
//   then: stage S(kt+2) into buf (kt+2)%3  (its readers finished at kt-1,
//         behind this barrier); asm ds_reads of buf kt%3;
//   s_waitcnt lgkmcnt(0) + sched_barrier(0)   (rule 18) ; MFMAs.
// Last step uses vmcnt(0). XOR swizzle chunk^=(row&7) both sides (proven).
// XCD swizzle: w=(bid&7)<<S|bid>>3 -> each XCD owns one expert (L2 locality).
// EPI=0: A1 = bf16(relu^2(C)).  EPI=1: out[tok] += gate * C (f32 atomics).
template<int KSTEPS, int EPI, int NT_TILES, int WPE_SHIFT>
__global__ __launch_bounds__(512, 1) void pass_gemm(
    const u16* __restrict__ Amat, const u16* __restrict__ Bmat,
    const int* __restrict__ bucket_tok, const float* __restrict__ bucket_gw,
    const int* __restrict__ ctrl,
    u16* __restrict__ A1out, float* __restrict__ out)
{
    const int K   = KSTEPS * 64;
    const int bid = blockIdx.x;
    const int w   = ((bid & 7) << WPE_SHIFT) | (bid >> 3);   // bijective chunked swizzle
    const int e   = w >> WPE_SHIFT;
    const int r   = w & ((1 << WPE_SHIFT) - 1);
    const int nt0 = (r % NT_TILES) * 128;                    // n fastest: A-panel L2 reuse
    const int mt0 = (r / NT_TILES) * 256;
    const int* offsets = ctrl + CTRL_OFFS;
    const int beg = offsets[e];
    const int cnt = offsets[e+1] - beg;
    if (mt0 >= cnt) return;

    extern __shared__ u16 sm[];   // 3 x { A[256][64] (32768 B) ; B[128][64] (16384 B) }

    const int tid  = threadIdx.x;
    const int wv   = tid >> 6;       // 0..7
    const int lane = tid & 63;
    const int l15  = lane & 15;
    const int grp  = lane >> 4;      // 0..3
    const int wr   = wv >> 1;        // 0..3  (m quarter: 64 rows)
    const int wc   = wv & 1;         // 0..1  (n half: 64 cols)
    const int rmax = cnt - mt0 - 1;

    const u16* Abase = Amat + (size_t)beg * K;
    const u16* Bb    = Bmat + (size_t)e * NH * ND;

    const int rsub8 = lane >> 3;     // row within 8-row group
    const int cs    = lane & 7;      // dest chunk (linear)

    // stage one K-tile: A 256 rows (4 instr/wave) + B 128 rows (2 instr/wave) = 6 VMEM/wave
    auto stage = [&](int buf, int kt) {
        u16* bA = sm + buf * 24576;
        u16* bB = bA + 16384;
        #pragma unroll
        for (int c = 0; c < 4; ++c) {
            int row   = wv*32 + c*8 + rsub8;          // 0..255
            int chunk = cs ^ (row & 7);               // inverse-swizzled source
            int lrow  = row > rmax ? rmax : row;
            gl_lds16(Abase + (size_t)(mt0 + lrow) * K + kt*64 + chunk*8, bA + wv*2048 + c*512);
        }
        #pragma unroll
        for (int c = 0; c < 2; ++c) {
            int row   = wv*16 + c*8 + rsub8;          // 0..127
            int chunk = cs ^ (row & 7);
            gl_lds16(Bb + (size_t)(nt0 + row) * K + kt*64 + chunk*8, bB + wv*1024 + c*512);
        }
    };

    // precomputed per-lane LDS byte offsets within a buffer
    unsigned aoff[2][4], boff[2][4];
    #pragma unroll
    for (int kk = 0; kk < 2; ++kk) {
        #pragma unroll
        for (int mt = 0; mt < 4; ++mt) {
            int row = wr*64 + mt*16 + l15;
            aoff[kk][mt] = (unsigned)(row*128 + (((kk*32 + grp*8)*2) ^ ((row & 7) << 4)));
        }
        #pragma unroll
        for (int nt = 0; nt < 4; ++nt) {
            int row = wc*64 + nt*16 + l15;
            boff[kk][nt] = (unsigned)(32768 + row*128 + (((kk*32 + grp*8)*2) ^ ((row & 7) << 4)));
        }
    }
    const unsigned smb = ldsoff(sm);

    f32x4 acc[4][4];
    #pragma unroll
    for (int mt = 0; mt < 4; ++mt)
        #pragma unroll
        for (int nt = 0; nt < 4; ++nt) acc[mt][nt] = 0;

    stage(0, 0);
    stage(1, 1);
    int bcur = 0;
    unsigned basecur = smb;
    for (int kt = 0; kt < KSTEPS; ++kt) {
        // counted wait: retires S(kt); keeps S(kt+1)'s 6 loads in flight
        if (kt + 1 < KSTEPS) { asm volatile("s_waitcnt vmcnt(6)" ::: "memory"); }
        else                 { asm volatile("s_waitcnt vmcnt(0)" ::: "memory"); }
        __builtin_amdgcn_s_barrier();
        __builtin_amdgcn_sched_barrier(0);

        // issue next-next tile's staging first (max flight time; its buffer's
        // readers all finished at step kt-1, behind the barrier above)
        if (kt + 2 < KSTEPS) {
            int bnx = bcur + 2; if (bnx >= 3) bnx -= 3;
            stage(bnx, kt + 2);
        }

        // compiler-invisible fragment reads (no auto vmcnt drain possible)
        bf16x8 af[2][4], bfr[2][4];
        #pragma unroll
        for (int kk = 0; kk < 2; ++kk) {
            #pragma unroll
            for (int mt = 0; mt < 4; ++mt)
                asm volatile("ds_read_b128 %0, %1"
                             : "=v"(af[kk][mt]) : "v"(basecur + aoff[kk][mt]));
            #pragma unroll
            for (int nt = 0; nt < 4; ++nt)
                asm volatile("ds_read_b128 %0, %1"
                             : "=v"(bfr[kk][nt]) : "v"(basecur + boff[kk][nt]));
        }
        asm volatile("s_waitcnt lgkmcnt(0)" ::: "memory");
        __builtin_amdgcn_sched_barrier(0);     // rule 18: pin MFMAs after the wait

        #pragma unroll
        for (int kk = 0; kk < 2; ++kk)
            #pragma unroll
            for (int mt = 0; mt < 4; ++mt)
                #pragma unroll
                for (int nt = 0; nt < 4; ++nt)
                    acc[mt][nt] = __builtin_amdgcn_mfma_f32_16x16x32_bf16(
                        af[kk][mt], bfr[kk][nt], acc[mt][nt], 0,0,0);

        bcur = (bcur == 2) ? 0 : bcur + 1;
        basecur = smb + (unsigned)bcur * 49152u;
    }

    // epilogue: D row(token) = grp*4+r, col = l15 (verified mapping)
    #pragma unroll
    for (int mt = 0; mt < 4; ++mt) {
        #pragma unroll
        for (int r4 = 0; r4 < 4; ++r4) {
            int ml = mt0 + wr*64 + mt*16 + grp*4 + r4;
            if (ml >= cnt) continue;
            if (EPI == 0) {
                u16* dst = A1out + (size_t)(beg + ml) * NH + nt0 + wc*64 + l15;
                #pragma unroll
                for (int nt = 0; nt < 4; ++nt) {
                    float v = fmaxf(acc[mt][nt][r4], 0.f);
                    dst[nt*16] = f2bf(v * v);
                }
            } else {
                int   p = bucket_tok[beg + ml];
                float g = bucket_gw [beg + ml];
                float* orow = out + (size_t)p * ND + nt0 + wc*64 + l15;
                #pragma unroll
                for (int nt = 0; nt < 4; ++nt)
                    atomicAdd(orow + nt*16, g * acc[mt][nt][r4]);
            }
        }
    }
}

// ---------------- launch ----------------
extern "C" void kernel_launch(void* const* d_in, const int* in_sizes, int n_in,
                              void* d_out, int out_size, void* d_ws, size_t ws_size,
                              hipStream_t stream) {
    const float* x  = (const float*)d_in[0];
    const float* rw = (const float*)d_in[1];
    const float* w1 = (const float*)d_in[2];
    const float* w2 = (const float*)d_in[3];
    float* out = (float*)d_out;

    int*   ctrl        = (int*)d_ws;
    int*   blockcounts = ctrl + CTRL_BC;
    int*   topk_idx    = ctrl + CTRL_TOPK;
    float* topk_w      = (float*)(topk_idx + NPAIR);
    int*   bucket_tok  = (int*)(topk_w + NPAIR);
    float* bucket_gw   = (float*)(bucket_tok + NPAIR);

    const size_t CTRL_BYTES = (size_t)1 << 19;                       // 512 KB
    const size_t WT_BYTES   = (size_t)NE * NH * ND * sizeof(u16);    // 32 MB

    hipMemsetAsync(d_out, 0, (size_t)NTOK * ND * sizeof(float), stream);

    router_topk2<<<NTOK/4, 256, 0, stream>>>(x, rw, topk_idx, topk_w);
    hist_blocks<<<NTOK/256, 256, 0, stream>>>(topk_idx, blockcounts);
    prefix2<<<1, 64, 0, stream>>>(ctrl);
    scatter2<<<NTOK/256, 256, 0, stream>>>(topk_idx, topk_w, ctrl, bucket_tok, bucket_gw);

    u16* w1t = (u16*)((char*)d_ws + CTRL_BYTES);
    u16* shr = (u16*)((char*)d_ws + CTRL_BYTES + WT_BYTES);      // Xg then w2t
    u16* A1  = (u16*)((char*)d_ws + CTRL_BYTES + 2*WT_BYTES);

    transpose_cvt<<<dim3(512, NE), 256, 0, stream>>>(w1, w1t, ND, NH);
    gather_cvt<<<NPAIR/4, 256, 0, stream>>>(x, bucket_tok, shr);

    const size_t shbytes = 3 * 24576 * sizeof(u16);   // 147456 B

    // pass 1: per-expert grid = 64 m-tiles (worst case) x 16 n-tiles = 1024 = 1<<10
    pass_gemm<16, 0, 16, 10><<<8 << 10, 512, shbytes, stream>>>(
        shr, w1t, bucket_tok, bucket_gw, ctrl, A1, nullptr);

    transpose_cvt<<<dim3(512, NE), 256, 0, stream>>>(w2, shr, NH, ND);

    // pass 2: per-expert grid = 64 m-tiles x 8 n-tiles = 512 = 1<<9
    pass_gemm<32, 1, 8, 9><<<8 << 9, 512, shbytes, stream>>>(
        A1, shr, bucket_tok, bucket_gw, ctrl, nullptr, out);
}

// Round 14
// 330.451 us; speedup vs baseline: 1.3352x; 1.0007x over previous
//
#include <hip/hip_runtime.h>
#include <hip/hip_bf16.h>
#include <stdint.h>

// MoELayer: B=4, T=2048, D=1024, E=8, H=2048, K=2
#define ND    1024
#define NE    8
#define NH    2048
#define NTOK  8192
#define NPAIR (NTOK*2)

typedef unsigned short u16;
typedef __attribute__((ext_vector_type(8))) short bf16x8;
typedef __attribute__((ext_vector_type(4))) float f32x4;

__device__ __forceinline__ u16 f2bf(float f) {
    union { float f; unsigned u; } v; v.f = f;
    return (u16)((v.u + 0x7fffu + ((v.u >> 16) & 1u)) >> 16);   // RNE
}

__device__ __forceinline__ void gl_lds16(const void* g, void* l) {
    __builtin_amdgcn_global_load_lds(
        (const __attribute__((address_space(1))) unsigned int*)g,
        (__attribute__((address_space(3))) unsigned int*)l, 16, 0, 0);
}

// LDS byte offset of an LDS pointer (AS(3) pointers are 32-bit offsets)
__device__ __forceinline__ unsigned ldsoff(const void* p) {
    return (unsigned)(size_t)(const __attribute__((address_space(3))) char*)p;
}

// ctrl layout (ints):
#define CTRL_OFFS  16
#define CTRL_BC    32
#define CTRL_BB    288
#define CTRL_TOPK  544

// ---------------- kernel 1: router (wave per token, NO atomics) ----------------
__global__ __launch_bounds__(256) void router_topk2(
    const float* __restrict__ x, const float* __restrict__ rw,
    int* __restrict__ topk_idx, float* __restrict__ topk_w)
{
    const int n    = blockIdx.x * 4 + (threadIdx.x >> 6);
    const int lane = threadIdx.x & 63;
    const float* xr = x + (size_t)n * ND;
    float4 xv[4];
    #pragma unroll
    for (int i = 0; i < 4; ++i) xv[i] = *(const float4*)(xr + lane*16 + i*4);

    float lg[NE];
    #pragma unroll
    for (int e = 0; e < NE; ++e) {
        const float* wr_ = rw + (size_t)e * ND + lane*16;
        float a = 0.f;
        #pragma unroll
        for (int i = 0; i < 4; ++i) {
            float4 wv = *(const float4*)(wr_ + i*4);
            a += xv[i].x*wv.x + xv[i].y*wv.y + xv[i].z*wv.z + xv[i].w*wv.w;
        }
        #pragma unroll
        for (int s = 32; s; s >>= 1) a += __shfl_xor(a, s);
        lg[e] = a;
    }
    if (lane == 0) {
        int i0 = 0; float v0 = lg[0];
        #pragma unroll
        for (int i = 1; i < NE; ++i) { float v = lg[i]; if (v > v0) { v0 = v; i0 = i; } }
        int i1 = -1; float v1 = -3.4e38f;
        #pragma unroll
        for (int i = 0; i < NE; ++i) {
            if (i == i0) continue;
            float v = lg[i]; if (v > v1) { v1 = v; i1 = i; }
        }
        float w0 = 1.f / (1.f + expf(v1 - v0));
        topk_idx[n*2]   = i0;  topk_idx[n*2+1] = i1;
        topk_w [n*2]    = w0;  topk_w [n*2+1]  = 1.f - w0;
    }
}

// ---------------- kernel 2: per-block expert histogram ----------------
__global__ __launch_bounds__(256) void hist_blocks(
    const int* __restrict__ topk_idx, int* __restrict__ blockcounts)
{
    __shared__ int c[NE];
    const int tid = threadIdx.x;
    if (tid < NE) c[tid] = 0;
    __syncthreads();
    const int n = blockIdx.x * 256 + tid;
    atomicAdd(&c[topk_idx[n*2]],   1);
    atomicAdd(&c[topk_idx[n*2+1]], 1);
    __syncthreads();
    if (tid < NE) blockcounts[blockIdx.x * NE + tid] = c[tid];
}

// ---------------- kernel 3: prefix (1 wave) ----------------
__global__ void prefix2(int* __restrict__ ctrl)
{
    const int e = threadIdx.x;
    const int* bc = ctrl + CTRL_BC;
    int* offsets  = ctrl + CTRL_OFFS;
    int* bbase    = ctrl + CTRL_BB;
    if (e < NE) {
        int run = 0;
        int tmp[32];
        #pragma unroll
        for (int b = 0; b < 32; ++b) { tmp[b] = run; run += bc[b*NE + e]; }
        int total = run, pre = 0;
        #pragma unroll
        for (int i = 0; i < NE; ++i) {
            int v = __shfl(total, i);
            if (i < e) pre += v;
        }
        offsets[e] = pre;
        if (e == NE-1) offsets[NE] = pre + total;
        #pragma unroll
        for (int b = 0; b < 32; ++b) bbase[b*NE + e] = pre + tmp[b];
    }
}

// ---------------- kernel 4: stable deterministic scatter ----------------
__global__ __launch_bounds__(256) void scatter2(
    const int* __restrict__ topk_idx, const float* __restrict__ topk_w,
    const int* __restrict__ ctrl,
    int* __restrict__ bucket_tok, float* __restrict__ bucket_gw)
{
    __shared__ int wc[4][NE];
    const int b = blockIdx.x, tid = threadIdx.x;
    const int w = tid >> 6, l = tid & 63;
    const int n = b*256 + tid;
    const int e0 = topk_idx[n*2], e1 = topk_idx[n*2+1];
    const unsigned long long lt = (1ULL << l) - 1ULL;

    int rank0 = 0, rank1 = 0;
    #pragma unroll
    for (int e = 0; e < NE; ++e) {
        unsigned long long m0 = __ballot(e0 == e);
        unsigned long long m1 = __ballot(e1 == e);
        int c0 = __popcll(m0);
        if (e0 == e) rank0 = __popcll(m0 & lt);
        if (e1 == e) rank1 = c0 + __popcll(m1 & lt);
        if (l == 0) wc[w][e] = c0 + __popcll(m1);
    }
    __syncthreads();
    const int* bbase = ctrl + CTRL_BB;
    int wo0 = 0, wo1 = 0;
    #pragma unroll
    for (int w2 = 0; w2 < 4; ++w2) {
        if (w2 < w) { wo0 += wc[w2][e0]; wo1 += wc[w2][e1]; }
    }
    int p0 = bbase[b*NE + e0] + wo0 + rank0;
    int p1 = bbase[b*NE + e1] + wo1 + rank1;
    bucket_tok[p0] = n;  bucket_gw[p0] = topk_w[n*2];
    bucket_tok[p1] = n;  bucket_gw[p1] = topk_w[n*2+1];
}

// ---------------- kernel T: transpose + fp32->bf16 ----------------
__global__ __launch_bounds__(256) void transpose_cvt(
    const float* __restrict__ src, u16* __restrict__ dst, int R, int C)
{
    __shared__ float tb[64][65];
    const int tpc = C >> 6;
    const int tr = blockIdx.x / tpc;
    const int tc = blockIdx.x % tpc;
    src += (size_t)blockIdx.y * R * C;
    dst += (size_t)blockIdx.y * R * C;
    const int tid = threadIdx.x;
    #pragma unroll
    for (int i = 0; i < 4; ++i) {
        int idx = i*256 + tid;
        int r = idx >> 4, c4 = (idx & 15) * 4;
        float4 v = *(const float4*)(src + (size_t)(tr*64 + r)*C + tc*64 + c4);
        tb[r][c4] = v.x; tb[r][c4+1] = v.y; tb[r][c4+2] = v.z; tb[r][c4+3] = v.w;
    }
    __syncthreads();
    #pragma unroll
    for (int i = 0; i < 2; ++i) {
        int idx = i*256 + tid;
        int c = idx >> 3, s8 = (idx & 7) * 8;
        union { u16 u[8]; uint4 v; } pk;
        #pragma unroll
        for (int j = 0; j < 8; ++j) pk.u[j] = f2bf(tb[s8 + j][c]);
        *(uint4*)(dst + (size_t)(tc*64 + c)*R + tr*64 + s8) = pk.v;
    }
}

// ---------------- kernel G: gather + fp32->bf16 ----------------
__global__ __launch_bounds__(256) void gather_cvt(
    const float* __restrict__ x, const int* __restrict__ bucket_tok, u16* __restrict__ Xg)
{
    const int pair = blockIdx.x * 4 + (threadIdx.x >> 6);
    const int lane = threadIdx.x & 63;
    const float* xr = x + (size_t)bucket_tok[pair] * ND;
    u16* dr = Xg + (size_t)pair * ND;
    const int d0 = lane * 16;
    float4 a = *(const float4*)(xr + d0);
    float4 b = *(const float4*)(xr + d0 + 4);
    float4 c = *(const float4*)(xr + d0 + 8);
    float4 d = *(const float4*)(xr + d0 + 12);
    union { u16 u[8]; uint4 v; } p0, p1;
    p0.u[0]=f2bf(a.x); p0.u[1]=f2bf(a.y); p0.u[2]=f2bf(a.z); p0.u[3]=f2bf(a.w);
    p0.u[4]=f2bf(b.x); p0.u[5]=f2bf(b.y); p0.u[6]=f2bf(b.z); p0.u[7]=f2bf(b.w);
    p1.u[0]=f2bf(c.x); p1.u[1]=f2bf(c.y); p1.u[2]=f2bf(c.z); p1.u[3]=f2bf(c.w);
    p1.u[4]=f2bf(d.x); p1.u[5]=f2bf(d.y); p1.u[6]=f2bf(d.z); p1.u[7]=f2bf(d.w);
    *(uint4*)(dr + d0)     = p0.v;
    *(uint4*)(dr + d0 + 8) = p1.v;
}

// ---------------- pass GEMM: 256m x 128n, BK=64, 8 waves, 3-buf counted-vmcnt ----------
// r9's proven-correct bookkeeping with COMPILER-INVISIBLE fragment reads:
// all 16 ds_read_b128 are inline asm (LDS byte offsets), so hipcc cannot
// insert its conservative vmcnt(0) drain between gl_lds staging and the
// reads (the r8/r9 stall). Ordering is carried entirely by explicit waits:
//   top of step kt: s_waitcnt vmcnt(6)  -> retires S(kt)   (S = 6 loads)
//                   s_barrier            -> true for all waves
//   then: stage S(kt+2) into buf (kt+2)%3  (its readers finished at kt-1,
//         behind this barrier); asm ds_reads of buf kt%3;
//   s_waitcnt lgkmcnt(0) + sched_barrier(0)   (rule 18) ; MFMAs.
// Last step uses vmcnt(0). XOR swizzle chunk^=(row&7) both sides (proven).
// XCD swizzle: w=(bid&7)<<S|bid>>3 -> each XCD owns one expert (L2 locality).
// EPI=0: A1 = bf16(relu^2(C)).  EPI=1: out[tok] += gate * C (f32 atomics).
template<int KSTEPS, int EPI, int NT_TILES, int WPE_SHIFT>
__global__ __launch_bounds__(512, 1) void pass_gemm(
    const u16* __restrict__ Amat, const u16* __restrict__ Bmat,
    const int* __restrict__ bucket_tok, const float* __restrict__ bucket_gw,
    const int* __restrict__ ctrl,
    u16* __restrict__ A1out, float* __restrict__ out)
{
    const int K   = KSTEPS * 64;
    const int bid = blockIdx.x;
    const int w   = ((bid & 7) << WPE_SHIFT) | (bid >> 3);   // bijective chunked swizzle
    const int e   = w >> WPE_SHIFT;
    const int r   = w & ((1 << WPE_SHIFT) - 1);
    const int nt0 = (r % NT_TILES) * 128;                    // n fastest: A-panel L2 reuse
    const int mt0 = (r / NT_TILES) * 256;
    const int* offsets = ctrl + CTRL_OFFS;
    const int beg = offsets[e];
    const int cnt = offsets[e+1] - beg;
    if (mt0 >= cnt) return;

    extern __shared__ u16 sm[];   // 3 x { A[256][64] (32768 B) ; B[128][64] (16384 B) }

    const int tid  = threadIdx.x;
    const int wv   = tid >> 6;       // 0..7
    const int lane = tid & 63;
    const int l15  = lane & 15;
    const int grp  = lane >> 4;      // 0..3
    const int wr   = wv >> 1;        // 0..3  (m quarter: 64 rows)
    const int wc   = wv & 1;         // 0..1  (n half: 64 cols)
    const int rmax = cnt - mt0 - 1;

    const u16* Abase = Amat + (size_t)beg * K;
    const u16* Bb    = Bmat + (size_t)e * NH * ND;

    const int rsub8 = lane >> 3;     // row within 8-row group
    const int cs    = lane & 7;      // dest chunk (linear)

    // stage one K-tile: A 256 rows (4 instr/wave) + B 128 rows (2 instr/wave) = 6 VMEM/wave
    auto stage = [&](int buf, int kt) {
        u16* bA = sm + buf * 24576;
        u16* bB = bA + 16384;
        #pragma unroll
        for (int c = 0; c < 4; ++c) {
            int row   = wv*32 + c*8 + rsub8;          // 0..255
            int chunk = cs ^ (row & 7);               // inverse-swizzled source
            int lrow  = row > rmax ? rmax : row;
            gl_lds16(Abase + (size_t)(mt0 + lrow) * K + kt*64 + chunk*8, bA + wv*2048 + c*512);
        }
        #pragma unroll
        for (int c = 0; c < 2; ++c) {
            int row   = wv*16 + c*8 + rsub8;          // 0..127
            int chunk = cs ^ (row & 7);
            gl_lds16(Bb + (size_t)(nt0 + row) * K + kt*64 + chunk*8, bB + wv*1024 + c*512);
        }
    };

    // precomputed per-lane LDS byte offsets within a buffer
    unsigned aoff[2][4], boff[2][4];
    #pragma unroll
    for (int kk = 0; kk < 2; ++kk) {
        #pragma unroll
        for (int mt = 0; mt < 4; ++mt) {
            int row = wr*64 + mt*16 + l15;
            aoff[kk][mt] = (unsigned)(row*128 + (((kk*32 + grp*8)*2) ^ ((row & 7) << 4)));
        }
        #pragma unroll
        for (int nt = 0; nt < 4; ++nt) {
            int row = wc*64 + nt*16 + l15;
            boff[kk][nt] = (unsigned)(32768 + row*128 + (((kk*32 + grp*8)*2) ^ ((row & 7) << 4)));
        }
    }
    const unsigned smb = ldsoff(sm);

    f32x4 acc[4][4];
    #pragma unroll
    for (int mt = 0; mt < 4; ++mt)
        #pragma unroll
        for (int nt = 0; nt < 4; ++nt) acc[mt][nt] = 0;

    stage(0, 0);
    stage(1, 1);
    int bcur = 0;
    unsigned basecur = smb;
    for (int kt = 0; kt < KSTEPS; ++kt) {
        // counted wait: retires S(kt); keeps S(kt+1)'s 6 loads in flight
        if (kt + 1 < KSTEPS) { asm volatile("s_waitcnt vmcnt(6)" ::: "memory"); }
        else                 { asm volatile("s_waitcnt vmcnt(0)" ::: "memory"); }
        __builtin_amdgcn_s_barrier();
        __builtin_amdgcn_sched_barrier(0);

        // issue next-next tile's staging first (max flight time; its buffer's
        // readers all finished at step kt-1, behind the barrier above)
        if (kt + 2 < KSTEPS) {
            int bnx = bcur + 2; if (bnx >= 3) bnx -= 3;
            stage(bnx, kt + 2);
        }

        // compiler-invisible fragment reads (no auto vmcnt drain possible)
        bf16x8 af[2][4], bfr[2][4];
        #pragma unroll
        for (int kk = 0; kk < 2; ++kk) {
            #pragma unroll
            for (int mt = 0; mt < 4; ++mt)
                asm volatile("ds_read_b128 %0, %1"
                             : "=v"(af[kk][mt]) : "v"(basecur + aoff[kk][mt]));
            #pragma unroll
            for (int nt = 0; nt < 4; ++nt)
                asm volatile("ds_read_b128 %0, %1"
                             : "=v"(bfr[kk][nt]) : "v"(basecur + boff[kk][nt]));
        }
        asm volatile("s_waitcnt lgkmcnt(0)" ::: "memory");
        __builtin_amdgcn_sched_barrier(0);     // rule 18: pin MFMAs after the wait

        #pragma unroll
        for (int kk = 0; kk < 2; ++kk)
            #pragma unroll
            for (int mt = 0; mt < 4; ++mt)
                #pragma unroll
                for (int nt = 0; nt < 4; ++nt)
                    acc[mt][nt] = __builtin_amdgcn_mfma_f32_16x16x32_bf16(
                        af[kk][mt], bfr[kk][nt], acc[mt][nt], 0,0,0);

        bcur = (bcur == 2) ? 0 : bcur + 1;
        basecur = smb + (unsigned)bcur * 49152u;
    }

    // epilogue: D row(token) = grp*4+r, col = l15 (verified mapping)
    #pragma unroll
    for (int mt = 0; mt < 4; ++mt) {
        #pragma unroll
        for (int r4 = 0; r4 < 4; ++r4) {
            int ml = mt0 + wr*64 + mt*16 + grp*4 + r4;
            if (ml >= cnt) continue;
            if (EPI == 0) {
                u16* dst = A1out + (size_t)(beg + ml) * NH + nt0 + wc*64 + l15;
                #pragma unroll
                for (int nt = 0; nt < 4; ++nt) {
                    float v = fmaxf(acc[mt][nt][r4], 0.f);
                    dst[nt*16] = f2bf(v * v);
                }
            } else {
                int   p = bucket_tok[beg + ml];
                float g = bucket_gw [beg + ml];
                float* orow = out + (size_t)p * ND + nt0 + wc*64 + l15;
                #pragma unroll
                for (int nt = 0; nt < 4; ++nt)
                    atomicAdd(orow + nt*16, g * acc[mt][nt][r4]);
            }
        }
    }
}

// ---------------- launch ----------------
extern "C" void kernel_launch(void* const* d_in, const int* in_sizes, int n_in,
                              void* d_out, int out_size, void* d_ws, size_t ws_size,
                              hipStream_t stream) {
    const float* x  = (const float*)d_in[0];
    const float* rw = (const float*)d_in[1];
    const float* w1 = (const float*)d_in[2];
    const float* w2 = (const float*)d_in[3];
    float* out = (float*)d_out;

    int*   ctrl        = (int*)d_ws;
    int*   blockcounts = ctrl + CTRL_BC;
    int*   topk_idx    = ctrl + CTRL_TOPK;
    float* topk_w      = (float*)(topk_idx + NPAIR);
    int*   bucket_tok  = (int*)(topk_w + NPAIR);
    float* bucket_gw   = (float*)(bucket_tok + NPAIR);

    const size_t CTRL_BYTES = (size_t)1 << 19;                       // 512 KB
    const size_t WT_BYTES   = (size_t)NE * NH * ND * sizeof(u16);    // 32 MB

    hipMemsetAsync(d_out, 0, (size_t)NTOK * ND * sizeof(float), stream);

    router_topk2<<<NTOK/4, 256, 0, stream>>>(x, rw, topk_idx, topk_w);
    hist_blocks<<<NTOK/256, 256, 0, stream>>>(topk_idx, blockcounts);
    prefix2<<<1, 64, 0, stream>>>(ctrl);
    scatter2<<<NTOK/256, 256, 0, stream>>>(topk_idx, topk_w, ctrl, bucket_tok, bucket_gw);

    u16* w1t = (u16*)((char*)d_ws + CTRL_BYTES);
    u16* shr = (u16*)((char*)d_ws + CTRL_BYTES + WT_BYTES);      // Xg then w2t
    u16* A1  = (u16*)((char*)d_ws + CTRL_BYTES + 2*WT_BYTES);

    transpose_cvt<<<dim3(512, NE), 256, 0, stream>>>(w1, w1t, ND, NH);
    gather_cvt<<<NPAIR/4, 256, 0, stream>>>(x, bucket_tok, shr);

    const size_t shbytes = 3 * 24576 * sizeof(u16);   // 147456 B

    // pass 1: per-expert grid = 64 m-tiles (worst case) x 16 n-tiles = 1024 = 1<<10
    pass_gemm<16, 0, 16, 10><<<8 << 10, 512, shbytes, stream>>>(
        shr, w1t, bucket_tok, bucket_gw, ctrl, A1, nullptr);

    transpose_cvt<<<dim3(512, NE), 256, 0, stream>>>(w2, shr, NH, ND);

    // pass 2: per-expert grid = 64 m-tiles x 8 n-tiles = 512 = 1<<9
    pass_gemm<32, 1, 8, 9><<<8 << 9, 512, shbytes, stream>>>(
        A1, shr, bucket_tok, bucket_gw, ctrl, nullptr, out);
}

// Round 15
// 285.623 us; speedup vs baseline: 1.5447x; 1.1569x over previous
//
#include <hip/hip_runtime.h>
#include <hip/hip_bf16.h>
#include <stdint.h>

// MoELayer: B=4, T=2048, D=1024, E=8, H=2048, K=2
#define ND    1024
#define NE    8
#define NH    2048
#define NTOK  8192
#define NPAIR (NTOK*2)

typedef unsigned short u16;
typedef __attribute__((ext_vector_type(8))) short bf16x8;
typedef __attribute__((ext_vector_type(4))) float f32x4;

__device__ __forceinline__ u16 f2bf(float f) {
    union { float f; unsigned u; } v; v.f = f;
    return (u16)((v.u + 0x7fffu + ((v.u >> 16) & 1u)) >> 16);   // RNE
}

__device__ __forceinline__ void gl_lds16(const void* g, void* l) {
    __builtin_amdgcn_global_load_lds(
        (const __attribute__((address_space(1))) unsigned int*)g,
        (__attribute__((address_space(3))) unsigned int*)l, 16, 0, 0);
}

// ctrl layout (ints):
#define CTRL_OFFS  16
#define CTRL_BC    32
#define CTRL_BB    288
#define CTRL_TOPK  544

// ---------------- kernel 1: router (wave per token, NO atomics) ----------------
__global__ __launch_bounds__(256) void router_topk2(
    const float* __restrict__ x, const float* __restrict__ rw,
    int* __restrict__ topk_idx, float* __restrict__ topk_w)
{
    const int n    = blockIdx.x * 4 + (threadIdx.x >> 6);
    const int lane = threadIdx.x & 63;
    const float* xr = x + (size_t)n * ND;
    float4 xv[4];
    #pragma unroll
    for (int i = 0; i < 4; ++i) xv[i] = *(const float4*)(xr + lane*16 + i*4);

    float lg[NE];
    #pragma unroll
    for (int e = 0; e < NE; ++e) {
        const float* wr_ = rw + (size_t)e * ND + lane*16;
        float a = 0.f;
        #pragma unroll
        for (int i = 0; i < 4; ++i) {
            float4 wv = *(const float4*)(wr_ + i*4);
            a += xv[i].x*wv.x + xv[i].y*wv.y + xv[i].z*wv.z + xv[i].w*wv.w;
        }
        #pragma unroll
        for (int s = 32; s; s >>= 1) a += __shfl_xor(a, s);
        lg[e] = a;
    }
    if (lane == 0) {
        int i0 = 0; float v0 = lg[0];
        #pragma unroll
        for (int i = 1; i < NE; ++i) { float v = lg[i]; if (v > v0) { v0 = v; i0 = i; } }
        int i1 = -1; float v1 = -3.4e38f;
        #pragma unroll
        for (int i = 0; i < NE; ++i) {
            if (i == i0) continue;
            float v = lg[i]; if (v > v1) { v1 = v; i1 = i; }
        }
        float w0 = 1.f / (1.f + expf(v1 - v0));
        topk_idx[n*2]   = i0;  topk_idx[n*2+1] = i1;
        topk_w [n*2]    = w0;  topk_w [n*2+1]  = 1.f - w0;
    }
}

// ---------------- kernel 2: per-block expert histogram ----------------
__global__ __launch_bounds__(256) void hist_blocks(
    const int* __restrict__ topk_idx, int* __restrict__ blockcounts)
{
    __shared__ int c[NE];
    const int tid = threadIdx.x;
    if (tid < NE) c[tid] = 0;
    __syncthreads();
    const int n = blockIdx.x * 256 + tid;
    atomicAdd(&c[topk_idx[n*2]],   1);
    atomicAdd(&c[topk_idx[n*2+1]], 1);
    __syncthreads();
    if (tid < NE) blockcounts[blockIdx.x * NE + tid] = c[tid];
}

// ---------------- kernel 3: prefix (1 wave) ----------------
__global__ void prefix2(int* __restrict__ ctrl)
{
    const int e = threadIdx.x;
    const int* bc = ctrl + CTRL_BC;
    int* offsets  = ctrl + CTRL_OFFS;
    int* bbase    = ctrl + CTRL_BB;
    if (e < NE) {
        int run = 0;
        int tmp[32];
        #pragma unroll
        for (int b = 0; b < 32; ++b) { tmp[b] = run; run += bc[b*NE + e]; }
        int total = run, pre = 0;
        #pragma unroll
        for (int i = 0; i < NE; ++i) {
            int v = __shfl(total, i);
            if (i < e) pre += v;
        }
        offsets[e] = pre;
        if (e == NE-1) offsets[NE] = pre + total;
        #pragma unroll
        for (int b = 0; b < 32; ++b) bbase[b*NE + e] = pre + tmp[b];
    }
}

// ---------------- kernel 4: stable deterministic scatter ----------------
__global__ __launch_bounds__(256) void scatter2(
    const int* __restrict__ topk_idx, const float* __restrict__ topk_w,
    const int* __restrict__ ctrl,
    int* __restrict__ bucket_tok, float* __restrict__ bucket_gw)
{
    __shared__ int wc[4][NE];
    const int b = blockIdx.x, tid = threadIdx.x;
    const int w = tid >> 6, l = tid & 63;
    const int n = b*256 + tid;
    const int e0 = topk_idx[n*2], e1 = topk_idx[n*2+1];
    const unsigned long long lt = (1ULL << l) - 1ULL;

    int rank0 = 0, rank1 = 0;
    #pragma unroll
    for (int e = 0; e < NE; ++e) {
        unsigned long long m0 = __ballot(e0 == e);
        unsigned long long m1 = __ballot(e1 == e);
        int c0 = __popcll(m0);
        if (e0 == e) rank0 = __popcll(m0 & lt);
        if (e1 == e) rank1 = c0 + __popcll(m1 & lt);
        if (l == 0) wc[w][e] = c0 + __popcll(m1);
    }
    __syncthreads();
    const int* bbase = ctrl + CTRL_BB;
    int wo0 = 0, wo1 = 0;
    #pragma unroll
    for (int w2 = 0; w2 < 4; ++w2) {
        if (w2 < w) { wo0 += wc[w2][e0]; wo1 += wc[w2][e1]; }
    }
    int p0 = bbase[b*NE + e0] + wo0 + rank0;
    int p1 = bbase[b*NE + e1] + wo1 + rank1;
    bucket_tok[p0] = n;  bucket_gw[p0] = topk_w[n*2];
    bucket_tok[p1] = n;  bucket_gw[p1] = topk_w[n*2+1];
}

// ---------------- kernel T: transpose + fp32->bf16 ----------------
__global__ __launch_bounds__(256) void transpose_cvt(
    const float* __restrict__ src, u16* __restrict__ dst, int R, int C)
{
    __shared__ float tb[64][65];
    const int tpc = C >> 6;
    const int tr = blockIdx.x / tpc;
    const int tc = blockIdx.x % tpc;
    src += (size_t)blockIdx.y * R * C;
    dst += (size_t)blockIdx.y * R * C;
    const int tid = threadIdx.x;
    #pragma unroll
    for (int i = 0; i < 4; ++i) {
        int idx = i*256 + tid;
        int r = idx >> 4, c4 = (idx & 15) * 4;
        float4 v = *(const float4*)(src + (size_t)(tr*64 + r)*C + tc*64 + c4);
        tb[r][c4] = v.x; tb[r][c4+1] = v.y; tb[r][c4+2] = v.z; tb[r][c4+3] = v.w;
    }
    __syncthreads();
    #pragma unroll
    for (int i = 0; i < 2; ++i) {
        int idx = i*256 + tid;
        int c = idx >> 3, s8 = (idx & 7) * 8;
        union { u16 u[8]; uint4 v; } pk;
        #pragma unroll
        for (int j = 0; j < 8; ++j) pk.u[j] = f2bf(tb[s8 + j][c]);
        *(uint4*)(dst + (size_t)(tc*64 + c)*R + tr*64 + s8) = pk.v;
    }
}

// ---------------- kernel X: fp32 -> bf16 convert of x (gather folded into pass1) -------
__global__ __launch_bounds__(256) void cvt_x(
    const float* __restrict__ x, u16* __restrict__ xbf)
{
    const int i = (blockIdx.x * 256 + threadIdx.x) * 8;
    float4 a = *(const float4*)(x + i);
    float4 b = *(const float4*)(x + i + 4);
    union { u16 u[8]; uint4 v; } p;
    p.u[0]=f2bf(a.x); p.u[1]=f2bf(a.y); p.u[2]=f2bf(a.z); p.u[3]=f2bf(a.w);
    p.u[4]=f2bf(b.x); p.u[5]=f2bf(b.y); p.u[6]=f2bf(b.z); p.u[7]=f2bf(b.w);
    *(uint4*)(xbf + i) = p.v;
}

// ---------------- pass GEMM: 128x128 tiles, NT layout, bf16 MFMA (r7 structure) --------
// PROVEN round-7 kernel (118us/GEMM): dbuf 64KB LDS, {sync; stage(next); compute(cur)},
// XOR swizzle chunk^=(row&7) via pre-swizzled global source + swizzled ds_read,
// XCD chunked swizzle w=(bid&7)<<S|bid>>3 -> each XCD owns one expert (L2 locality).
// NEW (only delta vs r7): GATHER=1 folds the token gather into A staging — the
// per-lane gl_lds source address indexes xbf via bucket_tok (4 prologue loads/thread),
// eliminating the separate gather_cvt pass.
// EPI=0: A1 = bf16(relu^2(C)).  EPI=1: out[tok] += gate * C (f32 atomics).
template<int KSTEPS, int EPI, int NT_TILES, int WPE_SHIFT, int GATHER>
__global__ __launch_bounds__(256, 2) void pass_gemm(
    const u16* __restrict__ Amat, const u16* __restrict__ Bmat,
    const int* __restrict__ bucket_tok, const float* __restrict__ bucket_gw,
    const int* __restrict__ ctrl,
    u16* __restrict__ A1out, float* __restrict__ out)
{
    const int K   = KSTEPS * 64;
    const int bid = blockIdx.x;
    const int w   = ((bid & 7) << WPE_SHIFT) | (bid >> 3);   // bijective chunked swizzle
    const int e   = w >> WPE_SHIFT;
    const int r   = w & ((1 << WPE_SHIFT) - 1);
    const int nt0 = (r % NT_TILES) * 128;                    // n fastest: A-panel L2 reuse
    const int mt0 = (r / NT_TILES) * 128;
    const int* offsets = ctrl + CTRL_OFFS;
    const int beg = offsets[e];
    const int cnt = offsets[e+1] - beg;
    if (mt0 >= cnt) return;

    extern __shared__ u16 sm[];   // A: [2][128][64] @0 ; B: [2][128][64] @16384 (u16 units)

    const int tid  = threadIdx.x;
    const int wv   = tid >> 6;
    const int lane = tid & 63;
    const int l15  = lane & 15;
    const int grp  = lane >> 4;
    const int wr   = wv >> 1, wc = wv & 1;
    const int rmax = cnt - mt0 - 1;

    const u16* Bb = Bmat + (size_t)e * NH * ND;

    const int rsub  = lane >> 3;     // row within 8-row group
    const int csrc0 = lane & 7;      // source chunk pre-swizzle

    // per-lane A row index (token-gathered for pass 1), one per c-iteration
    int arow[4];
    #pragma unroll
    for (int c = 0; c < 4; ++c) {
        int row = c*32 + wv*8 + rsub;
        int lrow = row > rmax ? rmax : row;
        arow[c] = GATHER ? bucket_tok[beg + mt0 + lrow] : (beg + mt0 + lrow);
    }

    auto stage = [&](int buf, int kt) {
        #pragma unroll
        for (int c = 0; c < 4; ++c) {
            int row = c*32 + wv*8 + rsub;
            int chunk = csrc0 ^ (row & 7);            // inverse-swizzled source
            const u16* ga = Amat + (size_t)arow[c] * K + kt*64 + chunk*8;
            gl_lds16(ga, sm + buf*8192 + c*2048 + wv*512);
            const u16* gb = Bb + (size_t)(nt0 + row) * K + kt*64 + chunk*8;
            gl_lds16(gb, sm + 16384 + buf*8192 + c*2048 + wv*512);
        }
    };

    f32x4 acc[4][4];
    #pragma unroll
    for (int mt = 0; mt < 4; ++mt)
        #pragma unroll
        for (int nt = 0; nt < 4; ++nt) acc[mt][nt] = 0;

    stage(0, 0);
    int cur = 0;
    for (int kt = 0; kt < KSTEPS; ++kt) {
        __syncthreads();                       // buf[cur] staged (vmcnt drain) + prev reads done
        if (kt + 1 < KSTEPS) stage(cur ^ 1, kt + 1);
        const char* As = (const char*)(sm + cur*8192);
        const char* Bs = (const char*)(sm + 16384 + cur*8192);
        #pragma unroll
        for (int kk = 0; kk < 2; ++kk) {
            bf16x8 af[4], bfr[4];
            #pragma unroll
            for (int mt = 0; mt < 4; ++mt) {
                int row = wr*64 + mt*16 + l15;
                int kb  = ((kk*32 + grp*8)*2) ^ ((row & 7) << 4);   // swizzled read
                af[mt] = *(const bf16x8*)(As + row*128 + kb);
            }
            #pragma unroll
            for (int nt = 0; nt < 4; ++nt) {
                int row = wc*64 + nt*16 + l15;
                int kb  = ((kk*32 + grp*8)*2) ^ ((row & 7) << 4);
                bfr[nt] = *(const bf16x8*)(Bs + row*128 + kb);
            }
            #pragma unroll
            for (int mt = 0; mt < 4; ++mt)
                #pragma unroll
                for (int nt = 0; nt < 4; ++nt)
                    acc[mt][nt] = __builtin_amdgcn_mfma_f32_16x16x32_bf16(af[mt], bfr[nt], acc[mt][nt], 0,0,0);
        }
        cur ^= 1;
    }

    // epilogue: D row(token) = grp*4+r, col = l15 (verified mapping)
    #pragma unroll
    for (int mt = 0; mt < 4; ++mt) {
        #pragma unroll
        for (int r4 = 0; r4 < 4; ++r4) {
            int ml = mt0 + wr*64 + mt*16 + grp*4 + r4;
            if (ml >= cnt) continue;
            if (EPI == 0) {
                u16* dst = A1out + (size_t)(beg + ml) * NH + nt0 + wc*64 + l15;
                #pragma unroll
                for (int nt = 0; nt < 4; ++nt) {
                    float v = fmaxf(acc[mt][nt][r4], 0.f);
                    dst[nt*16] = f2bf(v * v);
                }
            } else {
                int   p = bucket_tok[beg + ml];
                float g = bucket_gw [beg + ml];
                float* orow = out + (size_t)p * ND + nt0 + wc*64 + l15;
                #pragma unroll
                for (int nt = 0; nt < 4; ++nt)
                    atomicAdd(orow + nt*16, g * acc[mt][nt][r4]);
            }
        }
    }
}

// ---------------- launch ----------------
extern "C" void kernel_launch(void* const* d_in, const int* in_sizes, int n_in,
                              void* d_out, int out_size, void* d_ws, size_t ws_size,
                              hipStream_t stream) {
    const float* x  = (const float*)d_in[0];
    const float* rw = (const float*)d_in[1];
    const float* w1 = (const float*)d_in[2];
    const float* w2 = (const float*)d_in[3];
    float* out = (float*)d_out;

    int*   ctrl        = (int*)d_ws;
    int*   blockcounts = ctrl + CTRL_BC;
    int*   topk_idx    = ctrl + CTRL_TOPK;
    float* topk_w      = (float*)(topk_idx + NPAIR);
    int*   bucket_tok  = (int*)(topk_w + NPAIR);
    float* bucket_gw   = (float*)(bucket_tok + NPAIR);

    const size_t CTRL_BYTES = (size_t)1 << 19;                       // 512 KB
    const size_t WT_BYTES   = (size_t)NE * NH * ND * sizeof(u16);    // 32 MB

    hipMemsetAsync(d_out, 0, (size_t)NTOK * ND * sizeof(float), stream);

    router_topk2<<<NTOK/4, 256, 0, stream>>>(x, rw, topk_idx, topk_w);
    hist_blocks<<<NTOK/256, 256, 0, stream>>>(topk_idx, blockcounts);
    prefix2<<<1, 64, 0, stream>>>(ctrl);
    scatter2<<<NTOK/256, 256, 0, stream>>>(topk_idx, topk_w, ctrl, bucket_tok, bucket_gw);

    u16* w1t = (u16*)((char*)d_ws + CTRL_BYTES);
    u16* shr = (u16*)((char*)d_ws + CTRL_BYTES + WT_BYTES);      // xbf (16MB) then w2t (32MB)
    u16* A1  = (u16*)((char*)d_ws + CTRL_BYTES + 2*WT_BYTES);

    transpose_cvt<<<dim3(512, NE), 256, 0, stream>>>(w1, w1t, ND, NH);
    cvt_x<<<NTOK*ND/2048, 256, 0, stream>>>(x, shr);             // xbf

    const size_t shbytes = 16384 * sizeof(u16);   // 32768 B x2 bufs = 65536

    // pass 1: A = xbf gathered in-staging via bucket_tok; grid = 128 m x 16 n = 1<<11 /expert
    pass_gemm<16, 0, 16, 11, 1><<<8 << 11, 256, 65536, stream>>>(
        shr, w1t, bucket_tok, bucket_gw, ctrl, A1, nullptr);

    transpose_cvt<<<dim3(512, NE), 256, 0, stream>>>(w2, shr, NH, ND);   // w2t (overwrites xbf)

    // pass 2: A = A1 direct; grid = 128 m x 8 n = 1<<10 /expert
    pass_gemm<32, 1, 8, 10, 0><<<8 << 10, 256, 65536, stream>>>(
        A1, shr, bucket_tok, bucket_gw, ctrl, nullptr, out);
}